// Round 4
// baseline (1022.141 us; speedup 1.0000x reference)
//
#include <hip/hip_runtime.h>

typedef unsigned short u16;
typedef unsigned int u32;
typedef __bf16 bf16;
typedef bf16 bf16x8 __attribute__((ext_vector_type(8)));
typedef float f32x4 __attribute__((ext_vector_type(4)));

#define CIN 384
#define C3 1152
#define NPIX 16384
#define NB 8
#define DH 48
#define IMG 128
#define BK 32
#define NKS (CIN / BK)   // 12 K-steps

__device__ __forceinline__ u16 f2bf(float f) {
  u32 u = __float_as_uint(f);
  u32 r = (u + 0x7fffu + ((u >> 16) & 1u)) >> 16;  // RNE
  return (u16)r;
}
__device__ __forceinline__ float bf2f(u16 a) { return __uint_as_float(((u32)a) << 16); }
__device__ __forceinline__ u32 pk(u16 a, u16 b) { return (u32)a | ((u32)b << 16); }

// async global->LDS, 16B per lane; LDS dest = wave-uniform base + lane*16
__device__ __forceinline__ void gload16(const u16* g, u16* l) {
  __builtin_amdgcn_global_load_lds((const __attribute__((address_space(1))) void*)g,
                                   (__attribute__((address_space(3))) void*)l, 16, 0, 0);
}

// ---------------- K-1: weights -> bf16 ----------------
__global__ __launch_bounds__(256) void k_wcvt(const float* __restrict__ wp,
                                              const float* __restrict__ wo,
                                              u16* __restrict__ wpb,
                                              u16* __restrict__ wob) {
  int i = blockIdx.x * 256 + threadIdx.x;
  if (i < C3 * CIN) wpb[i] = f2bf(wp[i]);
  if (i < CIN * CIN) wob[i] = f2bf(wo[i]);
}

// ---------------- K0: fused LN stats + normalize + transpose -> xn_t[b][p][c] bf16 ----------------
__global__ __launch_bounds__(256) void k_norm(const float* __restrict__ x,
                                              const float* __restrict__ lnw,
                                              u16* __restrict__ xnt) {
  int idx = blockIdx.x * 256 + threadIdx.x;   // B*N = 131072
  int b = idx >> 14, p = idx & (NPIX - 1);
  const float* xp = x + (size_t)b * CIN * NPIX + p;
  float s = 0.f, s2 = 0.f;
#pragma unroll 4
  for (int c = 0; c < CIN; ++c) {
    float v = xp[(size_t)c * NPIX];
    s += v; s2 += v * v;
  }
  float m = s * (1.f / CIN);
  float rs = rsqrtf(s2 * (1.f / CIN) - m * m + 1e-5f);
  u16* op = xnt + (size_t)idx * CIN;
  for (int c0 = 0; c0 < CIN; c0 += 16) {   // second pass: L2/L3-resident re-reads
    u16 t[16];
#pragma unroll
    for (int i = 0; i < 16; ++i)
      t[i] = f2bf((xp[(size_t)(c0 + i) * NPIX] - m) * rs * lnw[c0 + i]);
    uint4 v0 = make_uint4(pk(t[0], t[1]), pk(t[2], t[3]), pk(t[4], t[5]), pk(t[6], t[7]));
    uint4 v1 = make_uint4(pk(t[8], t[9]), pk(t[10], t[11]), pk(t[12], t[13]), pk(t[14], t[15]));
    *(uint4*)&op[c0] = v0;
    *(uint4*)&op[c0 + 8] = v1;
  }
}

// ---------------- K1: pointwise conv GEMM (dbuf global_load_lds, 2-phase) ----------------
// qkv_pre[b][o][p] = sum_c Wb[o][c] * xn_t[b][p][c]
// LDS: [row][BK], 16B chunk at slot (chunk + (row>>1))&3 (conflict-free frag reads).
// gload_lds writes linearly -> SOURCE chunk pre-swizzled: ck = ((l&3)-((l>>3)&3))&3.
// 2-phase: stage tile t+1 into buf^1 BEFORE computing tile t; one barrier/step —
// global-load latency hides under ds_read+MFMA (T3-minimum template).
__global__ __launch_bounds__(256) void k_pconv(const u16* __restrict__ wpb,
                                               const u16* __restrict__ xnt,
                                               u16* __restrict__ qkv_pre) {
  __shared__ u16 As[2][128 * BK];
  __shared__ u16 Bs[2][128 * BK];
  int blk = blockIdx.x;
  int pt = blk & 127;
  int ot = (blk >> 7) % 9;
  int b = blk / (9 * 128);
  int o0 = ot * 128, p0 = pt * 128;
  int tid = threadIdx.x;
  int lane = tid & 63, wave = tid >> 6;
  int ml = lane & 15, quad = lane >> 4;
  int wm = (wave & 1) * 64, wn = (wave >> 1) * 64;

  int lr = lane >> 2;                              // row within 16-row segment
  int ck = ((lane & 3) - ((lane >> 3) & 3)) & 3;   // pre-swizzled source chunk
  const u16* srcA0 = wpb + (size_t)(o0 + 32 * wave + lr) * CIN + ck * 8;
  const u16* srcA1 = srcA0 + (size_t)16 * CIN;
  const u16* srcB0 = xnt + ((size_t)((b << 14) + p0 + 32 * wave + lr)) * CIN + ck * 8;
  const u16* srcB1 = srcB0 + (size_t)16 * CIN;
  int dOff0 = (32 * wave) * BK, dOff1 = (32 * wave + 16) * BK;

  f32x4 acc[4][4];
#pragma unroll
  for (int i = 0; i < 4; ++i)
#pragma unroll
    for (int j = 0; j < 4; ++j) acc[i][j] = (f32x4){0.f, 0.f, 0.f, 0.f};

  auto stg = [&](int bi, int kc) {
    gload16(srcA0 + kc, &As[bi][dOff0]);
    gload16(srcA1 + kc, &As[bi][dOff1]);
    gload16(srcB0 + kc, &Bs[bi][dOff0]);
    gload16(srcB1 + kc, &Bs[bi][dOff1]);
  };
  auto cmp = [&](int bi) {
    bf16x8 af[4], bfr[4];
#pragma unroll
    for (int mt = 0; mt < 4; ++mt) {
      int rw = wm + mt * 16 + ml;
      af[mt] = *(const bf16x8*)&As[bi][rw * BK + (((quad + (rw >> 1)) & 3) * 8)];
    }
#pragma unroll
    for (int nt = 0; nt < 4; ++nt) {
      int rw = wn + nt * 16 + ml;
      bfr[nt] = *(const bf16x8*)&Bs[bi][rw * BK + (((quad + (rw >> 1)) & 3) * 8)];
    }
#pragma unroll
    for (int mt = 0; mt < 4; ++mt)
#pragma unroll
      for (int nt = 0; nt < 4; ++nt)
        acc[mt][nt] = __builtin_amdgcn_mfma_f32_16x16x32_bf16(af[mt], bfr[nt], acc[mt][nt], 0, 0, 0);
  };

  stg(0, 0);
  __syncthreads();                 // drains prologue loads
  for (int t = 0; t < NKS - 1; ++t) {
    stg((t & 1) ^ 1, (t + 1) * BK);  // issue next tile BEFORE compute
    cmp(t & 1);
    __syncthreads();               // vmcnt(0) drain overlapped by cmp
  }
  cmp((NKS - 1) & 1);

#pragma unroll
  for (int mt = 0; mt < 4; ++mt)
#pragma unroll
    for (int nt = 0; nt < 4; ++nt) {
      int o = o0 + wm + mt * 16 + quad * 4;
      int p = p0 + wn + nt * 16 + ml;
      size_t base = ((size_t)(b * C3 + o)) * NPIX + p;
#pragma unroll
      for (int r = 0; r < 4; ++r)
        qkv_pre[base + (size_t)r * NPIX] = f2bf(acc[mt][nt][r]);
    }
}

// ---------------- K2: depthwise 3x3 — 8x4 px/thread, shfl edge exchange ----------------
__global__ __launch_bounds__(256) void k_dconv(const u16* __restrict__ pre,
                                               const float* __restrict__ wd,
                                               u16* __restrict__ post) {
  int bidx = blockIdx.x;
  int cg = bidx >> 1;                 // b*C3 + ch   (2 blocks per channel image)
  int half = bidx & 1;
  int ch = cg % C3;
  int tid = threadIdx.x;
  int xl = tid & 15;
  int y0 = half * 64 + (tid >> 4) * 4;
  int x0 = xl * 8;
  const u16* pb = pre + (size_t)cg * NPIX;
  const float* wc = wd + ch * 9;
  float w[9];
#pragma unroll
  for (int i = 0; i < 9; ++i) w[i] = wc[i];

  uint4 v[6];
#pragma unroll
  for (int r = 0; r < 6; ++r) {
    int yy = y0 + r - 1;
    bool ok = ((unsigned)yy < (unsigned)IMG);
    const u16* row = pb + yy * IMG + x0;
    v[r] = ok ? *(const uint4*)row : make_uint4(0u, 0u, 0u, 0u);
  }

  float acc[4][8];
#pragma unroll
  for (int j = 0; j < 4; ++j)
#pragma unroll
    for (int i = 0; i < 8; ++i) acc[j][i] = 0.f;

#pragma unroll
  for (int r = 0; r < 6; ++r) {
    // neighbor-lane edge pixels (lane-1 holds x0-1, lane+1 holds x0+8)
    u32 lw = (u32)__shfl_up((int)v[r].w, 1);    // prev lane elems 6,7
    u32 rw = (u32)__shfl_down((int)v[r].x, 1);  // next lane elems 0,1
    float rr[10];
    const u16* pv = (const u16*)&v[r];
    rr[0] = (xl > 0) ? bf2f((u16)(lw >> 16)) : 0.f;
    rr[9] = (xl < 15) ? bf2f((u16)(rw & 0xffffu)) : 0.f;
#pragma unroll
    for (int i = 0; i < 8; ++i) rr[i + 1] = bf2f(pv[i]);
#pragma unroll
    for (int j = 0; j < 4; ++j) {
      int ky = r - j;
      if (ky < 0 || ky > 2) continue;    // constant-folded (both loops unrolled)
      float w0 = w[ky * 3 + 0], w1 = w[ky * 3 + 1], w2 = w[ky * 3 + 2];
#pragma unroll
      for (int i = 0; i < 8; ++i)
        acc[j][i] += rr[i] * w0 + rr[i + 1] * w1 + rr[i + 2] * w2;
    }
  }
#pragma unroll
  for (int j = 0; j < 4; ++j) {
    u16 o[8];
#pragma unroll
    for (int i = 0; i < 8; ++i) o[i] = f2bf(acc[j][i]);
    uint4 ov = make_uint4(pk(o[0], o[1]), pk(o[2], o[3]), pk(o[4], o[5]), pk(o[6], o[7]));
    *(uint4*)(post + (size_t)cg * NPIX + (y0 + j) * IMG + x0) = ov;
  }
}

// ---------------- K3: Q^T K split-K partials ----------------
__global__ __launch_bounds__(64) void k_score(const u16* __restrict__ post,
                                              float* __restrict__ partial) {
  int blk = blockIdx.x;  // bh*64 + chunk
  int chunk = blk & 63, bh = blk >> 6;
  int b = bh >> 3, h = bh & 7;
  int lane = threadIdx.x;
  int ml = lane & 15, quad = lane >> 4;
  int n0 = chunk * 256;
  const u16* qp[3];
  const u16* kp[3];
#pragma unroll
  for (int t = 0; t < 3; ++t) {
    qp[t] = post + ((size_t)(b * C3 + h * DH + t * 16 + ml)) * NPIX + n0 + quad * 8;
    kp[t] = post + ((size_t)(b * C3 + CIN + h * DH + t * 16 + ml)) * NPIX + n0 + quad * 8;
  }
  f32x4 acc[3][3];
#pragma unroll
  for (int i = 0; i < 3; ++i)
#pragma unroll
    for (int j = 0; j < 3; ++j) acc[i][j] = (f32x4){0.f, 0.f, 0.f, 0.f};
  for (int ks = 0; ks < 256; ks += 32) {
    bf16x8 qf[3], kf[3];
#pragma unroll
    for (int t = 0; t < 3; ++t) {
      qf[t] = *(const bf16x8*)(qp[t] + ks);
      kf[t] = *(const bf16x8*)(kp[t] + ks);
    }
#pragma unroll
    for (int it = 0; it < 3; ++it)
#pragma unroll
      for (int jt = 0; jt < 3; ++jt)
        acc[it][jt] = __builtin_amdgcn_mfma_f32_16x16x32_bf16(qf[it], kf[jt], acc[it][jt], 0, 0, 0);
  }
  float* pp = partial + (size_t)blk * (DH * DH);
#pragma unroll
  for (int it = 0; it < 3; ++it)
#pragma unroll
    for (int jt = 0; jt < 3; ++jt)
#pragma unroll
      for (int r = 0; r < 4; ++r)
        pp[(it * 16 + quad * 4 + r) * DH + jt * 16 + ml] = acc[it][jt][r];
}

// ---------------- K4: reduce partials, softmax, emit score^T (K-padded) ----------------
__global__ __launch_bounds__(256) void k_softmax(const float* __restrict__ partial,
                                                 const float* __restrict__ alpha,
                                                 u16* __restrict__ scoreT) {
  __shared__ float sc[DH * DH];
  __shared__ float pr[DH * DH];
  int bh = blockIdx.x, tid = threadIdx.x;
  const float* pp = partial + (size_t)bh * 64 * (DH * DH);
  for (int e = tid; e < DH * DH; e += 256) {
    float s = 0.f;
    for (int c = 0; c < 64; ++c) s += pp[(size_t)c * (DH * DH) + e];
    sc[e] = s;
  }
  __syncthreads();
  float inv_a = 1.0f / alpha[0];
  if (tid < DH) {
    int i = tid;
    float mx = -1e30f;
    for (int j = 0; j < DH; ++j) mx = fmaxf(mx, sc[i * DH + j] * inv_a);
    float sum = 0.f;
    for (int j = 0; j < DH; ++j) {
      float e = __expf(sc[i * DH + j] * inv_a - mx);
      pr[i * DH + j] = e;
      sum += e;
    }
    float r = 1.f / sum;
    for (int j = 0; j < DH; ++j) pr[i * DH + j] *= r;
  }
  __syncthreads();
  u16* st = scoreT + (size_t)bh * DH * 64;
  for (int e = tid; e < DH * 64; e += 256) {
    int j = e >> 6, i = e & 63;
    st[e] = f2bf(i < DH ? pr[i * DH + j] : 0.f);  // zero-pad K to 64
  }
}

// ---------------- K5: attn_t[b][p][c] = sum_i score^T[j][i] * v[i][n] ----------------
#define VS_LD 72
__global__ __launch_bounds__(256) void k_attnv(const u16* __restrict__ post,
                                               const u16* __restrict__ scoreT,
                                               u16* __restrict__ attn_t) {
  __shared__ u16 Vs[128 * VS_LD];  // V^T tile: [n][i], i-contig
  int blk = blockIdx.x;
  int pt = blk & 127, h = (blk >> 7) & 7, b = blk >> 10;
  int p0 = pt * 128;
  int tid = threadIdx.x, lane = tid & 63, wave = tid >> 6;
  int ml = lane & 15, quad = lane >> 4;
  {  // stage V transposed: thread owns one n, 32 i's (clamped to valid channels)
    int n = tid & 127;
    int i0 = (tid >> 7) * 32;
    size_t vbase = ((size_t)(b * C3 + 2 * CIN + h * DH)) * NPIX + p0 + n;
    u16 t[32];
#pragma unroll
    for (int i = 0; i < 32; ++i) {
      int ic = i0 + i;
      int icc = ic < DH ? ic : (DH - 1);   // i>=DH multiplied by zero score
      t[i] = post[vbase + (size_t)icc * NPIX];
    }
#pragma unroll
    for (int q2 = 0; q2 < 4; ++q2) {
      uint4 v = make_uint4(pk(t[q2 * 8 + 0], t[q2 * 8 + 1]), pk(t[q2 * 8 + 2], t[q2 * 8 + 3]),
                           pk(t[q2 * 8 + 4], t[q2 * 8 + 5]), pk(t[q2 * 8 + 6], t[q2 * 8 + 7]));
      *(uint4*)&Vs[n * VS_LD + i0 + q2 * 8] = v;
    }
  }
  __syncthreads();
  const u16* sT = scoreT + (size_t)(b * 8 + h) * (DH * 64);
  int wn = wave * 32;
  f32x4 acc[3][2];
#pragma unroll
  for (int i = 0; i < 3; ++i)
#pragma unroll
    for (int j = 0; j < 2; ++j) acc[i][j] = (f32x4){0.f, 0.f, 0.f, 0.f};
#pragma unroll
  for (int ks = 0; ks < 2; ++ks) {
    bf16x8 a3[3], b2[2];
#pragma unroll
    for (int mt = 0; mt < 3; ++mt)
      a3[mt] = *(const bf16x8*)&sT[(mt * 16 + ml) * 64 + ks * 32 + quad * 8];
#pragma unroll
    for (int nt = 0; nt < 2; ++nt)
      b2[nt] = *(const bf16x8*)&Vs[(wn + nt * 16 + ml) * VS_LD + ks * 32 + quad * 8];
#pragma unroll
    for (int mt = 0; mt < 3; ++mt)
#pragma unroll
      for (int nt = 0; nt < 2; ++nt)
        acc[mt][nt] = __builtin_amdgcn_mfma_f32_16x16x32_bf16(a3[mt], b2[nt], acc[mt][nt], 0, 0, 0);
  }
#pragma unroll
  for (int mt = 0; mt < 3; ++mt)
#pragma unroll
    for (int nt = 0; nt < 2; ++nt) {
      int j0 = mt * 16 + quad * 4;
      int n = wn + nt * 16 + ml;
      u16 o4[4];
#pragma unroll
      for (int r = 0; r < 4; ++r) o4[r] = f2bf(acc[mt][nt][r]);
      uint2 ov = make_uint2(pk(o4[0], o4[1]), pk(o4[2], o4[3]));
      *(uint2*)&attn_t[((size_t)((b << 14) + p0 + n)) * CIN + h * DH + j0] = ov;
    }
}

// ---------------- K6: output GEMM + residual (dbuf global_load_lds, 2-phase) ----------------
__global__ __launch_bounds__(256) void k_out(const u16* __restrict__ wob,
                                             const u16* __restrict__ attn_t,
                                             const float* __restrict__ x,
                                             float* __restrict__ out) {
  __shared__ u16 As[2][128 * BK];
  __shared__ u16 Bs[2][128 * BK];
  int blk = blockIdx.x;
  int pt = blk & 127;
  int ot = (blk >> 7) % 3;
  int b = blk / (3 * 128);
  int o0 = ot * 128, p0 = pt * 128;
  int tid = threadIdx.x;
  int lane = tid & 63, wave = tid >> 6;
  int ml = lane & 15, quad = lane >> 4;
  int wm = (wave & 1) * 64, wn = (wave >> 1) * 64;

  int lr = lane >> 2;
  int ck = ((lane & 3) - ((lane >> 3) & 3)) & 3;
  const u16* srcA0 = wob + (size_t)(o0 + 32 * wave + lr) * CIN + ck * 8;
  const u16* srcA1 = srcA0 + (size_t)16 * CIN;
  const u16* srcB0 = attn_t + ((size_t)((b << 14) + p0 + 32 * wave + lr)) * CIN + ck * 8;
  const u16* srcB1 = srcB0 + (size_t)16 * CIN;
  int dOff0 = (32 * wave) * BK, dOff1 = (32 * wave + 16) * BK;

  f32x4 acc[4][4];
#pragma unroll
  for (int i = 0; i < 4; ++i)
#pragma unroll
    for (int j = 0; j < 4; ++j) acc[i][j] = (f32x4){0.f, 0.f, 0.f, 0.f};

  auto stg = [&](int bi, int kc) {
    gload16(srcA0 + kc, &As[bi][dOff0]);
    gload16(srcA1 + kc, &As[bi][dOff1]);
    gload16(srcB0 + kc, &Bs[bi][dOff0]);
    gload16(srcB1 + kc, &Bs[bi][dOff1]);
  };
  auto cmp = [&](int bi) {
    bf16x8 af[4], bfr[4];
#pragma unroll
    for (int mt = 0; mt < 4; ++mt) {
      int rw = wm + mt * 16 + ml;
      af[mt] = *(const bf16x8*)&As[bi][rw * BK + (((quad + (rw >> 1)) & 3) * 8)];
    }
#pragma unroll
    for (int nt = 0; nt < 4; ++nt) {
      int rw = wn + nt * 16 + ml;
      bfr[nt] = *(const bf16x8*)&Bs[bi][rw * BK + (((quad + (rw >> 1)) & 3) * 8)];
    }
#pragma unroll
    for (int mt = 0; mt < 4; ++mt)
#pragma unroll
      for (int nt = 0; nt < 4; ++nt)
        acc[mt][nt] = __builtin_amdgcn_mfma_f32_16x16x32_bf16(af[mt], bfr[nt], acc[mt][nt], 0, 0, 0);
  };

  stg(0, 0);
  __syncthreads();
  for (int t = 0; t < NKS - 1; ++t) {
    stg((t & 1) ^ 1, (t + 1) * BK);
    cmp(t & 1);
    __syncthreads();
  }
  cmp((NKS - 1) & 1);

#pragma unroll
  for (int mt = 0; mt < 4; ++mt)
#pragma unroll
    for (int nt = 0; nt < 4; ++nt) {
      int o = o0 + wm + mt * 16 + quad * 4;
      int p = p0 + wn + nt * 16 + ml;
      size_t base = ((size_t)(b * CIN + o)) * NPIX + p;
#pragma unroll
      for (int r = 0; r < 4; ++r) {
        size_t gi = base + (size_t)r * NPIX;
        out[gi] = acc[mt][nt][r] + x[gi];
      }
    }
}

extern "C" void kernel_launch(void* const* d_in, const int* in_sizes, int n_in,
                              void* d_out, int out_size, void* d_ws, size_t ws_size,
                              hipStream_t stream) {
  const float* x = (const float*)d_in[0];
  const float* lnw = (const float*)d_in[1];
  const float* wp = (const float*)d_in[2];
  const float* wd = (const float*)d_in[3];
  const float* wo = (const float*)d_in[4];
  const float* alpha = (const float*)d_in[5];
  float* out = (float*)d_out;

  // ws layout (bytes), total 605,159,424:
  //   [0, 884736)                  wpb  (bf16 1152x384)
  //   [884736, 1179648)            wob  (bf16 384x384)
  //   [1179648, +301,989,888)      qkv_pre (bf16); dead after dconv, re-used as:
  //        attn_t  at +0          (100,663,296)
  //        partial at +100663296  (37,748,736)
  //        scoreT  at +138412032.. (393,216)
  //   [303,169,536, +301,989,888)  qkv_post (bf16)
  // xn_t (bf16 [b][p][c], 100.7MB) lives in d_out (dead until k_out writes it).
  char* ws = (char*)d_ws;
  u16* wpb = (u16*)ws;
  u16* wob = (u16*)(ws + 884736);
  u16* qkv_pre = (u16*)(ws + 1179648);
  u16* attn_t = qkv_pre;
  float* partial = (float*)(ws + 1179648 + 100663296);
  u16* scoreT = (u16*)(ws + 1179648 + 100663296 + 37748736);
  u16* qkv_post = (u16*)(ws + 303169536);
  u16* xnt = (u16*)d_out;

  hipLaunchKernelGGL(k_wcvt, dim3(1728), dim3(256), 0, stream, wp, wo, wpb, wob);
  hipLaunchKernelGGL(k_norm, dim3(512), dim3(256), 0, stream, x, lnw, xnt);
  hipLaunchKernelGGL(k_pconv, dim3(NB * 9 * 128), dim3(256), 0, stream, wpb, xnt, qkv_pre);
  hipLaunchKernelGGL(k_dconv, dim3(NB * C3 * 2), dim3(256), 0, stream, qkv_pre, wd, qkv_post);
  hipLaunchKernelGGL(k_score, dim3(64 * 64), dim3(64), 0, stream, qkv_post, partial);
  hipLaunchKernelGGL(k_softmax, dim3(64), dim3(256), 0, stream, partial, alpha, scoreT);
  hipLaunchKernelGGL(k_attnv, dim3(NB * 8 * 128), dim3(256), 0, stream, qkv_post, scoreT, attn_t);
  hipLaunchKernelGGL(k_out, dim3(NB * 3 * 128), dim3(256), 0, stream, wob, attn_t, x, out);
}

// Round 5
// 972.713 us; speedup vs baseline: 1.0508x; 1.0508x over previous
//
#include <hip/hip_runtime.h>

typedef unsigned short u16;
typedef unsigned int u32;
typedef __bf16 bf16;
typedef bf16 bf16x8 __attribute__((ext_vector_type(8)));
typedef float f32x4 __attribute__((ext_vector_type(4)));

#define CIN 384
#define C3 1152
#define NPIX 16384
#define NB 8
#define DH 48
#define IMG 128
#define BK 32
#define NKS (CIN / BK)   // 12 K-steps

__device__ __forceinline__ u16 f2bf(float f) {
  u32 u = __float_as_uint(f);
  u32 r = (u + 0x7fffu + ((u >> 16) & 1u)) >> 16;  // RNE
  return (u16)r;
}
__device__ __forceinline__ float bf2f(u16 a) { return __uint_as_float(((u32)a) << 16); }
__device__ __forceinline__ u32 pk(u16 a, u16 b) { return (u32)a | ((u32)b << 16); }

// async global->LDS, 16B per lane; LDS dest = wave-uniform base + lane*16
__device__ __forceinline__ void gload16(const u16* g, u16* l) {
  __builtin_amdgcn_global_load_lds((const __attribute__((address_space(1))) void*)g,
                                   (__attribute__((address_space(3))) void*)l, 16, 0, 0);
}

// ---------------- K-1: weights -> bf16 ----------------
__global__ __launch_bounds__(256) void k_wcvt(const float* __restrict__ wp,
                                              const float* __restrict__ wo,
                                              u16* __restrict__ wpb,
                                              u16* __restrict__ wob) {
  int i = blockIdx.x * 256 + threadIdx.x;
  if (i < C3 * CIN) wpb[i] = f2bf(wp[i]);
  if (i < CIN * CIN) wob[i] = f2bf(wo[i]);
}

// ---------------- K0: fused LN stats + normalize + transpose -> xn_t[b][p][c] bf16 ----------------
__global__ __launch_bounds__(256) void k_norm(const float* __restrict__ x,
                                              const float* __restrict__ lnw,
                                              u16* __restrict__ xnt) {
  int idx = blockIdx.x * 256 + threadIdx.x;   // B*N = 131072
  int b = idx >> 14, p = idx & (NPIX - 1);
  const float* xp = x + (size_t)b * CIN * NPIX + p;
  float s = 0.f, s2 = 0.f;
#pragma unroll 4
  for (int c = 0; c < CIN; ++c) {
    float v = xp[(size_t)c * NPIX];
    s += v; s2 += v * v;
  }
  float m = s * (1.f / CIN);
  float rs = rsqrtf(s2 * (1.f / CIN) - m * m + 1e-5f);
  u16* op = xnt + (size_t)idx * CIN;
  for (int c0 = 0; c0 < CIN; c0 += 16) {   // second pass: L2/L3-resident re-reads
    u16 t[16];
#pragma unroll
    for (int i = 0; i < 16; ++i)
      t[i] = f2bf((xp[(size_t)(c0 + i) * NPIX] - m) * rs * lnw[c0 + i]);
    uint4 v0 = make_uint4(pk(t[0], t[1]), pk(t[2], t[3]), pk(t[4], t[5]), pk(t[6], t[7]));
    uint4 v1 = make_uint4(pk(t[8], t[9]), pk(t[10], t[11]), pk(t[12], t[13]), pk(t[14], t[15]));
    *(uint4*)&op[c0] = v0;
    *(uint4*)&op[c0 + 8] = v1;
  }
}

// ---------------- K1: pointwise conv GEMM — 8 waves/tile, acc[4][2] ----------------
// qkv_pre[b][o][p] = sum_c Wb[o][c] * xn_t[b][p][c]
// 128x128 tile, 512 threads: wave (w>>2,w&3) owns a 64x32 sub-tile -> 32 AGPR acc
// (was 64) so 4+ waves/SIMD fit: occupancy-driven latency hiding.
// LDS [row][BK], chunk slot (c+(row>>1))&3; gload_lds writes linearly so the
// SOURCE chunk is pre-swizzled (caveat #21): ck = ((l&3)-((l>>3)&3))&3.
__global__ __launch_bounds__(512, 4) void k_pconv(const u16* __restrict__ wpb,
                                                  const u16* __restrict__ xnt,
                                                  u16* __restrict__ qkv_pre) {
  __shared__ u16 As[2][128 * BK];
  __shared__ u16 Bs[2][128 * BK];
  int blk = blockIdx.x;
  int pt = blk & 127;
  int ot = (blk >> 7) % 9;
  int b = blk / (9 * 128);
  int o0 = ot * 128, p0 = pt * 128;
  int tid = threadIdx.x;
  int lane = tid & 63, wave = tid >> 6;          // 8 waves
  int ml = lane & 15, quad = lane >> 4;
  int wm = (wave >> 2) * 64;                     // 2 M-groups of 64
  int wn = (wave & 3) * 32;                      // 4 N-groups of 32

  int lr = lane >> 2;                            // row within 16-row segment
  int ck = ((lane & 3) - ((lane >> 3) & 3)) & 3; // pre-swizzled source chunk
  const u16* srcA = wpb + (size_t)(o0 + 16 * wave + lr) * CIN + ck * 8;
  const u16* srcB = xnt + ((size_t)((b << 14) + p0 + 16 * wave + lr)) * CIN + ck * 8;
  int dOff = (16 * wave) * BK;

  f32x4 acc[4][2];
#pragma unroll
  for (int i = 0; i < 4; ++i)
#pragma unroll
    for (int j = 0; j < 2; ++j) acc[i][j] = (f32x4){0.f, 0.f, 0.f, 0.f};

  auto stg = [&](int bi, int kc) {
    gload16(srcA + kc, &As[bi][dOff]);
    gload16(srcB + kc, &Bs[bi][dOff]);
  };
  auto cmp = [&](int bi) {
    bf16x8 af[4], bfr[2];
#pragma unroll
    for (int mt = 0; mt < 4; ++mt) {
      int rw = wm + mt * 16 + ml;
      af[mt] = *(const bf16x8*)&As[bi][rw * BK + (((quad + (rw >> 1)) & 3) * 8)];
    }
#pragma unroll
    for (int nt = 0; nt < 2; ++nt) {
      int rw = wn + nt * 16 + ml;
      bfr[nt] = *(const bf16x8*)&Bs[bi][rw * BK + (((quad + (rw >> 1)) & 3) * 8)];
    }
#pragma unroll
    for (int mt = 0; mt < 4; ++mt)
#pragma unroll
      for (int nt = 0; nt < 2; ++nt)
        acc[mt][nt] = __builtin_amdgcn_mfma_f32_16x16x32_bf16(af[mt], bfr[nt], acc[mt][nt], 0, 0, 0);
  };

  stg(0, 0);
  __syncthreads();
  for (int t = 0; t < NKS - 1; ++t) {
    stg((t & 1) ^ 1, (t + 1) * BK);
    cmp(t & 1);
    __syncthreads();
  }
  cmp((NKS - 1) & 1);

#pragma unroll
  for (int mt = 0; mt < 4; ++mt)
#pragma unroll
    for (int nt = 0; nt < 2; ++nt) {
      int o = o0 + wm + mt * 16 + quad * 4;
      int p = p0 + wn + nt * 16 + ml;
      size_t base = ((size_t)(b * C3 + o)) * NPIX + p;
#pragma unroll
      for (int r = 0; r < 4; ++r)
        qkv_pre[base + (size_t)r * NPIX] = f2bf(acc[mt][nt][r]);
    }
}

// ---------------- K2: depthwise 3x3 — 8x4 px/thread, shfl edge exchange ----------------
__global__ __launch_bounds__(256) void k_dconv(const u16* __restrict__ pre,
                                               const float* __restrict__ wd,
                                               u16* __restrict__ post) {
  int bidx = blockIdx.x;
  int cg = bidx >> 1;                 // b*C3 + ch   (2 blocks per channel image)
  int half = bidx & 1;
  int ch = cg % C3;
  int tid = threadIdx.x;
  int xl = tid & 15;
  int y0 = half * 64 + (tid >> 4) * 4;
  int x0 = xl * 8;
  const u16* pb = pre + (size_t)cg * NPIX;
  const float* wc = wd + ch * 9;
  float w[9];
#pragma unroll
  for (int i = 0; i < 9; ++i) w[i] = wc[i];

  uint4 v[6];
#pragma unroll
  for (int r = 0; r < 6; ++r) {
    int yy = y0 + r - 1;
    bool ok = ((unsigned)yy < (unsigned)IMG);
    const u16* row = pb + yy * IMG + x0;
    v[r] = ok ? *(const uint4*)row : make_uint4(0u, 0u, 0u, 0u);
  }

  float acc[4][8];
#pragma unroll
  for (int j = 0; j < 4; ++j)
#pragma unroll
    for (int i = 0; i < 8; ++i) acc[j][i] = 0.f;

#pragma unroll
  for (int r = 0; r < 6; ++r) {
    // neighbor-lane edge pixels (lane-1 holds x0-1, lane+1 holds x0+8)
    u32 lw = (u32)__shfl_up((int)v[r].w, 1);    // prev lane elems 6,7
    u32 rw = (u32)__shfl_down((int)v[r].x, 1);  // next lane elems 0,1
    float rr[10];
    const u16* pv = (const u16*)&v[r];
    rr[0] = (xl > 0) ? bf2f((u16)(lw >> 16)) : 0.f;
    rr[9] = (xl < 15) ? bf2f((u16)(rw & 0xffffu)) : 0.f;
#pragma unroll
    for (int i = 0; i < 8; ++i) rr[i + 1] = bf2f(pv[i]);
#pragma unroll
    for (int j = 0; j < 4; ++j) {
      int ky = r - j;
      if (ky < 0 || ky > 2) continue;    // constant-folded (both loops unrolled)
      float w0 = w[ky * 3 + 0], w1 = w[ky * 3 + 1], w2 = w[ky * 3 + 2];
#pragma unroll
      for (int i = 0; i < 8; ++i)
        acc[j][i] += rr[i] * w0 + rr[i + 1] * w1 + rr[i + 2] * w2;
    }
  }
#pragma unroll
  for (int j = 0; j < 4; ++j) {
    u16 o[8];
#pragma unroll
    for (int i = 0; i < 8; ++i) o[i] = f2bf(acc[j][i]);
    uint4 ov = make_uint4(pk(o[0], o[1]), pk(o[2], o[3]), pk(o[4], o[5]), pk(o[6], o[7]));
    *(uint4*)(post + (size_t)cg * NPIX + (y0 + j) * IMG + x0) = ov;
  }
}

// ---------------- K3: Q^T K split-K partials ----------------
__global__ __launch_bounds__(64) void k_score(const u16* __restrict__ post,
                                              float* __restrict__ partial) {
  int blk = blockIdx.x;  // bh*64 + chunk
  int chunk = blk & 63, bh = blk >> 6;
  int b = bh >> 3, h = bh & 7;
  int lane = threadIdx.x;
  int ml = lane & 15, quad = lane >> 4;
  int n0 = chunk * 256;
  const u16* qp[3];
  const u16* kp[3];
#pragma unroll
  for (int t = 0; t < 3; ++t) {
    qp[t] = post + ((size_t)(b * C3 + h * DH + t * 16 + ml)) * NPIX + n0 + quad * 8;
    kp[t] = post + ((size_t)(b * C3 + CIN + h * DH + t * 16 + ml)) * NPIX + n0 + quad * 8;
  }
  f32x4 acc[3][3];
#pragma unroll
  for (int i = 0; i < 3; ++i)
#pragma unroll
    for (int j = 0; j < 3; ++j) acc[i][j] = (f32x4){0.f, 0.f, 0.f, 0.f};
  for (int ks = 0; ks < 256; ks += 32) {
    bf16x8 qf[3], kf[3];
#pragma unroll
    for (int t = 0; t < 3; ++t) {
      qf[t] = *(const bf16x8*)(qp[t] + ks);
      kf[t] = *(const bf16x8*)(kp[t] + ks);
    }
#pragma unroll
    for (int it = 0; it < 3; ++it)
#pragma unroll
      for (int jt = 0; jt < 3; ++jt)
        acc[it][jt] = __builtin_amdgcn_mfma_f32_16x16x32_bf16(qf[it], kf[jt], acc[it][jt], 0, 0, 0);
  }
  float* pp = partial + (size_t)blk * (DH * DH);
#pragma unroll
  for (int it = 0; it < 3; ++it)
#pragma unroll
    for (int jt = 0; jt < 3; ++jt)
#pragma unroll
      for (int r = 0; r < 4; ++r)
        pp[(it * 16 + quad * 4 + r) * DH + jt * 16 + ml] = acc[it][jt][r];
}

// ---------------- K4: reduce partials, softmax, emit score^T (K-padded) ----------------
__global__ __launch_bounds__(256) void k_softmax(const float* __restrict__ partial,
                                                 const float* __restrict__ alpha,
                                                 u16* __restrict__ scoreT) {
  __shared__ float sc[DH * DH];
  __shared__ float pr[DH * DH];
  int bh = blockIdx.x, tid = threadIdx.x;
  const float* pp = partial + (size_t)bh * 64 * (DH * DH);
  for (int e = tid; e < DH * DH; e += 256) {
    float s = 0.f;
    for (int c = 0; c < 64; ++c) s += pp[(size_t)c * (DH * DH) + e];
    sc[e] = s;
  }
  __syncthreads();
  float inv_a = 1.0f / alpha[0];
  if (tid < DH) {
    int i = tid;
    float mx = -1e30f;
    for (int j = 0; j < DH; ++j) mx = fmaxf(mx, sc[i * DH + j] * inv_a);
    float sum = 0.f;
    for (int j = 0; j < DH; ++j) {
      float e = __expf(sc[i * DH + j] * inv_a - mx);
      pr[i * DH + j] = e;
      sum += e;
    }
    float r = 1.f / sum;
    for (int j = 0; j < DH; ++j) pr[i * DH + j] *= r;
  }
  __syncthreads();
  u16* st = scoreT + (size_t)bh * DH * 64;
  for (int e = tid; e < DH * 64; e += 256) {
    int j = e >> 6, i = e & 63;
    st[e] = f2bf(i < DH ? pr[i * DH + j] : 0.f);  // zero-pad K to 64
  }
}

// ---------------- K5: attn_t[b][p][c] = sum_i score^T[j][i] * v[i][n] ----------------
#define VS_LD 72
__global__ __launch_bounds__(256) void k_attnv(const u16* __restrict__ post,
                                               const u16* __restrict__ scoreT,
                                               u16* __restrict__ attn_t) {
  __shared__ u16 Vs[128 * VS_LD];  // V^T tile: [n][i], i-contig
  int blk = blockIdx.x;
  int pt = blk & 127, h = (blk >> 7) & 7, b = blk >> 10;
  int p0 = pt * 128;
  int tid = threadIdx.x, lane = tid & 63, wave = tid >> 6;
  int ml = lane & 15, quad = lane >> 4;
  {  // stage V transposed: thread owns one n, 32 i's (clamped to valid channels)
    int n = tid & 127;
    int i0 = (tid >> 7) * 32;
    size_t vbase = ((size_t)(b * C3 + 2 * CIN + h * DH)) * NPIX + p0 + n;
    u16 t[32];
#pragma unroll
    for (int i = 0; i < 32; ++i) {
      int ic = i0 + i;
      int icc = ic < DH ? ic : (DH - 1);   // i>=DH multiplied by zero score
      t[i] = post[vbase + (size_t)icc * NPIX];
    }
#pragma unroll
    for (int q2 = 0; q2 < 4; ++q2) {
      uint4 v = make_uint4(pk(t[q2 * 8 + 0], t[q2 * 8 + 1]), pk(t[q2 * 8 + 2], t[q2 * 8 + 3]),
                           pk(t[q2 * 8 + 4], t[q2 * 8 + 5]), pk(t[q2 * 8 + 6], t[q2 * 8 + 7]));
      *(uint4*)&Vs[n * VS_LD + i0 + q2 * 8] = v;
    }
  }
  __syncthreads();
  const u16* sT = scoreT + (size_t)(b * 8 + h) * (DH * 64);
  int wn = wave * 32;
  f32x4 acc[3][2];
#pragma unroll
  for (int i = 0; i < 3; ++i)
#pragma unroll
    for (int j = 0; j < 2; ++j) acc[i][j] = (f32x4){0.f, 0.f, 0.f, 0.f};
#pragma unroll
  for (int ks = 0; ks < 2; ++ks) {
    bf16x8 a3[3], b2[2];
#pragma unroll
    for (int mt = 0; mt < 3; ++mt)
      a3[mt] = *(const bf16x8*)&sT[(mt * 16 + ml) * 64 + ks * 32 + quad * 8];
#pragma unroll
    for (int nt = 0; nt < 2; ++nt)
      b2[nt] = *(const bf16x8*)&Vs[(wn + nt * 16 + ml) * VS_LD + ks * 32 + quad * 8];
#pragma unroll
    for (int mt = 0; mt < 3; ++mt)
#pragma unroll
      for (int nt = 0; nt < 2; ++nt)
        acc[mt][nt] = __builtin_amdgcn_mfma_f32_16x16x32_bf16(a3[mt], b2[nt], acc[mt][nt], 0, 0, 0);
  }
#pragma unroll
  for (int mt = 0; mt < 3; ++mt)
#pragma unroll
    for (int nt = 0; nt < 2; ++nt) {
      int j0 = mt * 16 + quad * 4;
      int n = wn + nt * 16 + ml;
      u16 o4[4];
#pragma unroll
      for (int r = 0; r < 4; ++r) o4[r] = f2bf(acc[mt][nt][r]);
      uint2 ov = make_uint2(pk(o4[0], o4[1]), pk(o4[2], o4[3]));
      *(uint2*)&attn_t[((size_t)((b << 14) + p0 + n)) * CIN + h * DH + j0] = ov;
    }
}

// ---------------- K6: output GEMM + residual — 8 waves/tile, acc[4][2] ----------------
__global__ __launch_bounds__(512, 4) void k_out(const u16* __restrict__ wob,
                                                const u16* __restrict__ attn_t,
                                                const float* __restrict__ x,
                                                float* __restrict__ out) {
  __shared__ u16 As[2][128 * BK];
  __shared__ u16 Bs[2][128 * BK];
  int blk = blockIdx.x;
  int pt = blk & 127;
  int ot = (blk >> 7) % 3;
  int b = blk / (3 * 128);
  int o0 = ot * 128, p0 = pt * 128;
  int tid = threadIdx.x;
  int lane = tid & 63, wave = tid >> 6;
  int ml = lane & 15, quad = lane >> 4;
  int wm = (wave >> 2) * 64;
  int wn = (wave & 3) * 32;

  int lr = lane >> 2;
  int ck = ((lane & 3) - ((lane >> 3) & 3)) & 3;
  const u16* srcA = wob + (size_t)(o0 + 16 * wave + lr) * CIN + ck * 8;
  const u16* srcB = attn_t + ((size_t)((b << 14) + p0 + 16 * wave + lr)) * CIN + ck * 8;
  int dOff = (16 * wave) * BK;

  f32x4 acc[4][2];
#pragma unroll
  for (int i = 0; i < 4; ++i)
#pragma unroll
    for (int j = 0; j < 2; ++j) acc[i][j] = (f32x4){0.f, 0.f, 0.f, 0.f};

  auto stg = [&](int bi, int kc) {
    gload16(srcA + kc, &As[bi][dOff]);
    gload16(srcB + kc, &Bs[bi][dOff]);
  };
  auto cmp = [&](int bi) {
    bf16x8 af[4], bfr[2];
#pragma unroll
    for (int mt = 0; mt < 4; ++mt) {
      int rw = wm + mt * 16 + ml;
      af[mt] = *(const bf16x8*)&As[bi][rw * BK + (((quad + (rw >> 1)) & 3) * 8)];
    }
#pragma unroll
    for (int nt = 0; nt < 2; ++nt) {
      int rw = wn + nt * 16 + ml;
      bfr[nt] = *(const bf16x8*)&Bs[bi][rw * BK + (((quad + (rw >> 1)) & 3) * 8)];
    }
#pragma unroll
    for (int mt = 0; mt < 4; ++mt)
#pragma unroll
      for (int nt = 0; nt < 2; ++nt)
        acc[mt][nt] = __builtin_amdgcn_mfma_f32_16x16x32_bf16(af[mt], bfr[nt], acc[mt][nt], 0, 0, 0);
  };

  stg(0, 0);
  __syncthreads();
  for (int t = 0; t < NKS - 1; ++t) {
    stg((t & 1) ^ 1, (t + 1) * BK);
    cmp(t & 1);
    __syncthreads();
  }
  cmp((NKS - 1) & 1);

#pragma unroll
  for (int mt = 0; mt < 4; ++mt)
#pragma unroll
    for (int nt = 0; nt < 2; ++nt) {
      int o = o0 + wm + mt * 16 + quad * 4;
      int p = p0 + wn + nt * 16 + ml;
      size_t base = ((size_t)(b * CIN + o)) * NPIX + p;
#pragma unroll
      for (int r = 0; r < 4; ++r) {
        size_t gi = base + (size_t)r * NPIX;
        out[gi] = acc[mt][nt][r] + x[gi];
      }
    }
}

extern "C" void kernel_launch(void* const* d_in, const int* in_sizes, int n_in,
                              void* d_out, int out_size, void* d_ws, size_t ws_size,
                              hipStream_t stream) {
  const float* x = (const float*)d_in[0];
  const float* lnw = (const float*)d_in[1];
  const float* wp = (const float*)d_in[2];
  const float* wd = (const float*)d_in[3];
  const float* wo = (const float*)d_in[4];
  const float* alpha = (const float*)d_in[5];
  float* out = (float*)d_out;

  // ws layout (bytes), total 605,159,424:
  //   [0, 884736)                  wpb  (bf16 1152x384)
  //   [884736, 1179648)            wob  (bf16 384x384)
  //   [1179648, +301,989,888)      qkv_pre (bf16); dead after dconv, re-used as:
  //        attn_t  at +0          (100,663,296)
  //        partial at +100663296  (37,748,736)
  //        scoreT  at +138412032.. (393,216)
  //   [303,169,536, +301,989,888)  qkv_post (bf16)
  // xn_t (bf16 [b][p][c], 100.7MB) lives in d_out (dead until k_out writes it).
  char* ws = (char*)d_ws;
  u16* wpb = (u16*)ws;
  u16* wob = (u16*)(ws + 884736);
  u16* qkv_pre = (u16*)(ws + 1179648);
  u16* attn_t = qkv_pre;
  float* partial = (float*)(ws + 1179648 + 100663296);
  u16* scoreT = (u16*)(ws + 1179648 + 100663296 + 37748736);
  u16* qkv_post = (u16*)(ws + 303169536);
  u16* xnt = (u16*)d_out;

  hipLaunchKernelGGL(k_wcvt, dim3(1728), dim3(256), 0, stream, wp, wo, wpb, wob);
  hipLaunchKernelGGL(k_norm, dim3(512), dim3(256), 0, stream, x, lnw, xnt);
  hipLaunchKernelGGL(k_pconv, dim3(NB * 9 * 128), dim3(512), 0, stream, wpb, xnt, qkv_pre);
  hipLaunchKernelGGL(k_dconv, dim3(NB * C3 * 2), dim3(256), 0, stream, qkv_pre, wd, qkv_post);
  hipLaunchKernelGGL(k_score, dim3(64 * 64), dim3(64), 0, stream, qkv_post, partial);
  hipLaunchKernelGGL(k_softmax, dim3(64), dim3(256), 0, stream, partial, alpha, scoreT);
  hipLaunchKernelGGL(k_attnv, dim3(NB * 8 * 128), dim3(256), 0, stream, qkv_post, scoreT, attn_t);
  hipLaunchKernelGGL(k_out, dim3(NB * 3 * 128), dim3(512), 0, stream, wob, attn_t, x, out);
}